// Round 5
// baseline (386.623 us; speedup 1.0000x reference)
//
#include <hip/hip_runtime.h>
#include <math.h>

typedef unsigned short u16;
typedef unsigned int   u32;
typedef float f32x4  __attribute__((ext_vector_type(4)));
typedef float f32x16 __attribute__((ext_vector_type(16)));
typedef __bf16 bf16x8 __attribute__((ext_vector_type(8)));
typedef __bf16 bf16x2 __attribute__((ext_vector_type(2)));

#define SEQ   2048
#define BATCH 4
#define NH    16
#define DK    64
#define DM    1024
#define MTOT  (SEQ*BATCH)   /* 8192 rows */
#define SCL_QK 0.18033688011116016f   /* log2(e)/sqrt(64), folded into Q proj */

#if __has_builtin(__builtin_amdgcn_exp2f)
#define EXP2(x) __builtin_amdgcn_exp2f(x)
#else
#define EXP2(x) exp2f(x)
#endif

// counted-vmcnt (token-literal form, used by attn3)
#define WAITCNT_VM(N) asm volatile("s_waitcnt vmcnt(" #N ")" ::: "memory")
#define BARRIER_FENCED() do {                                  \
    asm volatile("" ::: "memory");                             \
    __builtin_amdgcn_s_barrier();                              \
    asm volatile("" ::: "memory");                             \
  } while (0)

// compile-time-N counted vmcnt for templated kernels
template<int N> static __device__ __forceinline__ void vm_wait() {
  if constexpr (N == 0)      asm volatile("s_waitcnt vmcnt(0)" ::: "memory");
  else if constexpr (N == 3) asm volatile("s_waitcnt vmcnt(3)" ::: "memory");
  else if constexpr (N == 4) asm volatile("s_waitcnt vmcnt(4)" ::: "memory");
  else if constexpr (N == 6) asm volatile("s_waitcnt vmcnt(6)" ::: "memory");
  else if constexpr (N == 8) asm volatile("s_waitcnt vmcnt(8)" ::: "memory");
  else static_assert(N == 0, "unsupported vmcnt");
}

static __device__ __forceinline__ u16 f2bf(float f) {
  __bf16 h = (__bf16)f;
  return __builtin_bit_cast(u16, h);
}
static __device__ __forceinline__ u32 pk2(float a, float b) {
  bf16x2 t = {(__bf16)a, (__bf16)b};          // -> v_cvt_pk_bf16_f32
  return __builtin_bit_cast(u32, t);
}

typedef __attribute__((address_space(1))) const void g1_t;
typedef __attribute__((address_space(3))) void l3_t;
static __device__ __forceinline__ void gload16(const void* g, void* l) {
  __builtin_amdgcn_global_load_lds((g1_t*)g, (l3_t*)l, 16, 0, 0);
}

static __device__ __forceinline__ void cast8(const float* __restrict__ src,
                                             u16* __restrict__ dst, int i) {
  float4 a = ((const float4*)src)[2 * i];
  float4 b = ((const float4*)src)[2 * i + 1];
  uint4 r;
  r.x = pk2(a.x, a.y); r.y = pk2(a.z, a.w);
  r.z = pk2(b.x, b.y); r.w = pk2(b.z, b.w);
  ((uint4*)dst)[i] = r;
}

__global__ __launch_bounds__(256)
void cast_bf16(const float* __restrict__ src, u16* __restrict__ dst, int n8) {
  int i = blockIdx.x * 256 + threadIdx.x;
  if (i < n8) cast8(src, dst, i);
}

__global__ __launch_bounds__(256)
void cast_w(const float* __restrict__ Wq, const float* __restrict__ Wk,
            const float* __restrict__ Wv, const float* __restrict__ Wo,
            u16* __restrict__ w3, u16* __restrict__ wo_c) {
  int bid = blockIdx.x;
  int t = bid >> 9, idx = bid & 511;
  const float* src = (t == 0) ? Wq : (t == 1) ? Wk : (t == 2) ? Wv : Wo;
  u16* dst = (t < 3) ? (w3 + (size_t)t * DM * DM) : wo_c;
  cast8(src, dst, idx * 256 + threadIdx.x);
}

__global__ __launch_bounds__(256)
void cast_all(const float* __restrict__ q, const float* __restrict__ k,
              const float* __restrict__ v,
              const float* __restrict__ Wq, const float* __restrict__ Wk,
              const float* __restrict__ Wv, const float* __restrict__ Wo,
              u16* __restrict__ in_c, u16* __restrict__ w3, u16* __restrict__ wo_c) {
  int bid = blockIdx.x;
  const float* src; u16* dst; int idx;
  if (bid < 12288) {
    int t = bid >> 12; idx = bid & 4095;
    src = (t == 0) ? q : (t == 1) ? k : v;
    dst = in_c + (size_t)t * MTOT * DM;
  } else {
    int wb = bid - 12288;
    int t = wb >> 9; idx = wb & 511;
    src = (t == 0) ? Wq : (t == 1) ? Wk : (t == 2) ? Wv : Wo;
    dst = (t < 3) ? (w3 + (size_t)t * DM * DM) : wo_c;
  }
  cast8(src, dst, idx * 256 + threadIdx.x);
}

// ---------------------------------------------------------------------------
// 8-phase 256-wide GEMM (T2+T3+T4+T5+T1). 512 thr = 8 waves (2M x 4N).
// BM=256; BN = 256 (OGEMM=0) / 128 (OGEMM=1). BK=64 as two K=32 half-tiles.
// LDS: As[2buf][2kk][256x32] (64KB) + Bs[2buf][2kk][BNx32] (64/32KB).
// Swizzle (T2, rule 21 both-sides): physical 16B-group g_phys = g_log ^ s(row),
// s(row) = (row&3)^((row>>2)&3). Staged via linear global_load_lds dst +
// inverse-swizzled per-lane GLOBAL source; ds_read applies the same XOR
// (per-lane constant since row%16 == l15 in fragment reads) -> 2-way max.
//
// Iter i (t=2i): 8 phases; phase = {frag ds-reads; stage 1 half; barrier;
// setprio(1) MFMA x(8*NG) setprio(0); [vmcnt]; barrier}.
//   ph1 (buf0,kk0,ng0) stage A[t+1]kk1->buf1      ph5 (buf1,kk0,ng0) stage A[t+2]kk1->buf0
//   ph2 (buf0,kk0,ng1) stage B[t+1]kk1->buf1 vm   ph6 (buf1,kk0,ng1) stage B[t+2]kk1->buf0 vm
//   ph3 (buf0,kk1,ng0) stage A[t+2]kk0->buf0      ph7 (buf1,kk1,ng0) stage A[t+3]kk0->buf1
//   ph4 (buf0,kk1,ng1) stage B[t+2]kk0->buf0 vm   ph8 (buf1,kk1,ng1) stage B[t+3]kk0->buf1 vm
// Liveness ledger: every stage overwrites a region whose last ds_read was
// >=1 full phase earlier (data already in regs before that phase's 2nd
// barrier, which precedes the stage's issue). vmcnt(VMN=LA+2LB) at even
// phases keeps the newest 3 half-tiles in flight and retires exactly the
// halves read 1-2 phases later (checked for steady state, prologue, and the
// peeled last iter with the VMN/VMM/0 ladder). Never vmcnt(0) in main loop.
template<int OGEMM>
__global__ __launch_bounds__(512, 2)
void gemm_k(const u16* __restrict__ a0, const u16* __restrict__ a1,
            const u16* __restrict__ a2, const u16* __restrict__ w3,
            const float* __restrict__ b0, const float* __restrict__ b1,
            const float* __restrict__ b2,
            u16* __restrict__ o0, u16* __restrict__ o1, u16* __restrict__ o2,
            float* __restrict__ o3, int seg_base)
{
  constexpr int BN   = OGEMM ? 128 : 256;
  constexpr int LB   = BN / 128;        // B-half loads/thread (A is 2)
  constexpr int NREP = BN / 64;         // 4 or 2 n-frags per wave
  constexpr int NG   = NREP / 2;        // n-frags per phase group
  constexpr int VMN  = 2 + 2 * LB;      // steady counted vmcnt (6 / 4)
  constexpr int VMM  = 2 + LB;          // last-iter mid (4 / 3)
  constexpr int VMP  = 2 * (2 + LB);    // prologue (8 / 6)
  constexpr int WCN  = BN / 4;          // per-wave col span
  constexpr int NKT  = DM / 64;         // 16 K-tiles
  constexpr int NI   = NKT / 2;         // 8 iterations

  __shared__ u16 As[2][2][256 * 32];
  __shared__ u16 Bs[2][2][BN * 32];

  // T1 chunked XCD swizzle (nwg = 384/256/128, all %8==0 -> bijective)
  const int nwg = gridDim.x * gridDim.y;
  const int bid = blockIdx.y * gridDim.x + blockIdx.x;
  const int swz = (bid & 7) * (nwg >> 3) + (bid >> 3);
  const int bx  = swz % gridDim.x;
  const int by  = swz / gridDim.x;

  const int seg = OGEMM ? 0 : (seg_base + (bx >> 2));
  const int n0  = OGEMM ? bx * BN : (bx & 3) * BN;
  const int m0  = by * 256;
  const u16* A = OGEMM ? a0 : (seg == 0 ? a0 : seg == 1 ? a1 : a2);
  const u16* W = OGEMM ? w3 : (w3 + (size_t)seg * DM * DM);
  const float* bias = OGEMM ? b0 : (seg == 0 ? b0 : seg == 1 ? b1 : b2);

  const int tid  = threadIdx.x;
  const int wid  = tid >> 6;
  const int lane = tid & 63;
  const int quad = lane >> 4;
  const int l15  = lane & 15;
  const int wr   = wid >> 2;            // 0..1
  const int wc   = wid & 3;             // 0..3

  // staging source (pre-swizzled global column group; LDS dst stays linear)
  const int rl = lane >> 2;
  const int gl = (lane & 3) ^ (((lane >> 2) & 3) ^ ((lane >> 4) & 3));
  size_t aoff[2], woff[LB];
#pragma unroll
  for (int p = 0; p < 2; p++) {
    int gm = m0 + p * 128 + wid * 16 + rl;
    if (OGEMM) aoff[p] = (size_t)gm * DM + gl * 8;
    else {
      int bb = gm >> 11, s = gm & (SEQ - 1);
      aoff[p] = (size_t)(s * BATCH + bb) * DM + gl * 8;
    }
  }
#pragma unroll
  for (int p = 0; p < LB; p++)
    woff[p] = (size_t)(n0 + p * 128 + wid * 16 + rl) * DM + gl * 8;

  // fragment ds_read bases (swizzled; XOR term is a per-lane constant)
  const int sr3   = (l15 & 3) ^ ((l15 >> 2) & 3);
  const int aro   = (quad ^ sr3) << 3;
  const int abase = (wr * 128 + l15) * 32 + aro;
  const int bbase = (wc * WCN + l15) * 32 + aro;

  f32x4 acc[8][NREP];
#pragma unroll
  for (int m = 0; m < 8; m++)
#pragma unroll
    for (int n = 0; n < NREP; n++)
      acc[m][n] = (f32x4){0.f, 0.f, 0.f, 0.f};

  bf16x8 afr[8], bfr[NREP];

#define STAGE_A(KT, KK, BUF) do {                                             \
    _Pragma("unroll") for (int p = 0; p < 2; p++)                             \
      gload16(A + aoff[p] + (KT) * 64 + (KK) * 32,                            \
              &As[BUF][KK][p * 4096 + wid * 512]);                            \
  } while (0)
#define STAGE_B(KT, KK, BUF) do {                                             \
    _Pragma("unroll") for (int p = 0; p < LB; p++)                            \
      gload16(W + woff[p] + (KT) * 64 + (KK) * 32,                            \
              &Bs[BUF][KK][p * 4096 + wid * 512]);                            \
  } while (0)
#define READA(BUF, KK) do {                                                   \
    _Pragma("unroll") for (int m = 0; m < 8; m++)                             \
      afr[m] = *(const bf16x8*)&As[BUF][KK][abase + m * 512];                 \
  } while (0)
#define READB(BUF, KK, NGI) do {                                              \
    _Pragma("unroll") for (int nn = 0; nn < NG; nn++)                         \
      bfr[(NGI) * NG + nn] =                                                  \
        *(const bf16x8*)&Bs[BUF][KK][bbase + ((NGI) * NG + nn) * 512];        \
  } while (0)
#define MFMAS(NGI) do {                                                       \
    __builtin_amdgcn_s_setprio(1);                                            \
    _Pragma("unroll") for (int m = 0; m < 8; m++)                             \
      _Pragma("unroll") for (int nn = 0; nn < NG; nn++)                       \
        acc[m][(NGI) * NG + nn] = __builtin_amdgcn_mfma_f32_16x16x32_bf16(    \
            afr[m], bfr[(NGI) * NG + nn], acc[m][(NGI) * NG + nn], 0, 0, 0);  \
    __builtin_amdgcn_s_setprio(0);                                            \
  } while (0)
#define PHASE(BUF, KK, NGI, STG, VMSTMT) do {                                 \
    if ((NGI) == 0) READA(BUF, KK);                                           \
    READB(BUF, KK, NGI);                                                      \
    STG;                                                                      \
    BARRIER_FENCED();                                                         \
    MFMAS(NGI);                                                               \
    VMSTMT;                                                                   \
    BARRIER_FENCED();                                                         \
  } while (0)
#define NOSTG ((void)0)
#define NOVM  ((void)0)

  // prologue: tiles 0 (both kk) + tile 1 kk0; wait for tile-0 kk0
  STAGE_A(0, 0, 0); STAGE_B(0, 0, 0);
  STAGE_A(0, 1, 0); STAGE_B(0, 1, 0);
  STAGE_A(1, 0, 1); STAGE_B(1, 0, 1);
  vm_wait<VMP>();
  BARRIER_FENCED();

  for (int i = 0; i < NI - 1; i++) {
    const int t = 2 * i;
    PHASE(0, 0, 0, STAGE_A(t + 1, 1, 1), NOVM);
    PHASE(0, 0, 1, STAGE_B(t + 1, 1, 1), vm_wait<VMN>());
    PHASE(0, 1, 0, STAGE_A(t + 2, 0, 0), NOVM);
    PHASE(0, 1, 1, STAGE_B(t + 2, 0, 0), vm_wait<VMN>());
    PHASE(1, 0, 0, STAGE_A(t + 2, 1, 0), NOVM);
    PHASE(1, 0, 1, STAGE_B(t + 2, 1, 0), vm_wait<VMN>());
    PHASE(1, 1, 0, STAGE_A(t + 3, 0, 1), NOVM);
    PHASE(1, 1, 1, STAGE_B(t + 3, 0, 1), vm_wait<VMN>());
  }
  // peeled last iter (t = NKT-2): only tile t+1 kk1 still needs staging
  PHASE(0, 0, 0, STAGE_A(NKT - 1, 1, 1), NOVM);
  PHASE(0, 0, 1, STAGE_B(NKT - 1, 1, 1), vm_wait<VMN>());
  PHASE(0, 1, 0, NOSTG, NOVM);
  PHASE(0, 1, 1, NOSTG, vm_wait<VMM>());
  PHASE(1, 0, 0, NOSTG, NOVM);
  PHASE(1, 0, 1, NOSTG, vm_wait<0>());
  PHASE(1, 1, 0, NOSTG, NOVM);
  PHASE(1, 1, 1, NOSTG, NOVM);

#undef STAGE_A
#undef STAGE_B
#undef READA
#undef READB
#undef MFMAS
#undef PHASE
#undef NOSTG
#undef NOVM

  // C/D layout: col(n) = lane&15, row(m) = quad*4 + reg
#pragma unroll
  for (int n = 0; n < NREP; n++) {
    int gn = n0 + wc * WCN + n * 16 + l15;
    float bv = bias[gn];
    int h = gn >> 6, dk = gn & 63;
#pragma unroll
    for (int m = 0; m < 8; m++) {
      int gmb = m0 + wr * 128 + m * 16 + quad * 4;
#pragma unroll
      for (int r = 0; r < 4; r++) {
        int gm = gmb + r;
        float val = acc[m][n][r] + bv;
        int bb = gm >> 11, s = gm & (SEQ - 1);
        if (OGEMM) {
          o3[(size_t)(s * BATCH + bb) * DM + gn] = val;
        } else if (seg == 0) {
          o0[((size_t)(bb * NH + h) * SEQ + s) * DK + dk] = f2bf(val * SCL_QK);
        } else if (seg == 1) {
          o1[((size_t)(bb * NH + h) * SEQ + s) * DK + dk] = f2bf(val);
        } else {
          o2[((size_t)(bb * NH + h) * DK + dk) * SEQ + s] = f2bf(val);
        }
      }
    }
  }
}

// ---------------------------------------------------------------------------
// Flash attention (round-4 version, unchanged): 32x32x16 MFMA, lane^32 P
// exchange, 2-buffer depth-1 K/V pipeline with counted vmcnt.
__global__ __launch_bounds__(256, 4)
void attn3(const u16* __restrict__ Q, const u16* __restrict__ K,
           const u16* __restrict__ VT, u16* __restrict__ ctx)
{
  __shared__ u16 Ks[2][64 * 64];
  __shared__ u16 Vs[2][64 * 64];

  const int bh = blockIdx.x;
  const int qt = blockIdx.y;
  const int b  = bh >> 4, h = bh & 15;
  const int tid  = threadIdx.x;
  const int w    = tid >> 6;
  const int lane = tid & 63;
  const int l31  = lane & 31;
  const int hi   = lane >> 5;

  const u16* Qb = Q  + (size_t)bh * SEQ * DK;
  const u16* Kb = K  + (size_t)bh * SEQ * DK;
  const u16* Vb = VT + (size_t)bh * DK * SEQ;

  const int qbase = qt * 128 + w * 32;
  const int qrow  = qbase + l31;

  bf16x8 qf[4];
#pragma unroll
  for (int ks = 0; ks < 4; ks++)
    qf[ks] = *(const bf16x8*)&Qb[(size_t)qrow * DK + ks * 16 + hi * 8];

  const int r0 = tid >> 3;
  const int sw = (tid & 7) ^ (r0 & 7);

#define STAGE(kbb, bufi) do {                                                       \
    _Pragma("unroll")                                                               \
    for (int p = 0; p < 2; p++) {                                                   \
      int row = p * 32 + r0;                                                        \
      gload16(&Kb[(size_t)((kbb) * 64 + row) * DK + sw * 8],                        \
              &Ks[bufi][(p * 32 + w * 8) * 64]);                                    \
      gload16(&Vb[(size_t)row * SEQ + (kbb) * 64 + sw * 8],                         \
              &Vs[bufi][(p * 32 + w * 8) * 64]);                                    \
    }                                                                               \
  } while (0)

  f32x16 z16;
#pragma unroll
  for (int i = 0; i < 16; i++) z16[i] = 0.f;

  f32x16 ot0 = z16, ot1 = z16;
  float2 ls2 = {0.f, 0.f};

  u32 wp[8];

#define SOFTMAX_BLK(SA) do {                                                        \
    _Pragma("unroll")                                                               \
    for (int g = 0; g < 8; g++) {                                                   \
      float pa = EXP2(SA[2 * g]);                                                   \
      float pb = EXP2(SA[2 * g + 1]);                                               \
      ls2.x += pa; ls2.y += pb;                                                     \
      wp[g] = pk2(pa, pb);                                                          \
    }                                                                               \
  } while (0)

#define PVSTEP(VsB, KSB, KSL) do {                                                  \
    u32 a0 = wp[(KSB) * 4 + 0], a1 = wp[(KSB) * 4 + 1];                             \
    u32 a2 = wp[(KSB) * 4 + 2], a3 = wp[(KSB) * 4 + 3];                             \
    u32 s0 = hi ? a0 : a2, s1 = hi ? a1 : a3;                                       \
    u32 x0 = (u32)__shfl_xor((int)s0, 32);                                          \
    u32 x1 = (u32)__shfl_xor((int)s1, 32);                                          \
    uint4 pw;                                                                       \
    pw.x = hi ? x0 : a0; pw.y = hi ? x1 : a1;                                       \
    pw.z = hi ? a2 : x0; pw.w = hi ? a3 : x1;                                       \
    bf16x8 pf = __builtin_bit_cast(bf16x8, pw);                                     \
    const int gg = (((KSL) * 2 + hi) ^ (l31 & 7)) * 8;                              \
    bf16x8 vf0 = *(const bf16x8*)&VsB[l31 * 64 + gg];                               \
    bf16x8 vf1 = *(const bf16x8*)&VsB[(32 + l31) * 64 + gg];                        \
    ot0 = __builtin_amdgcn_mfma_f32_32x32x16_bf16(vf0, pf, ot0, 0, 0, 0);           \
    ot1 = __builtin_amdgcn_mfma_f32_32x32x16_bf16(vf1, pf, ot1, 0, 0, 0);           \
  } while (0)

#define BODY(curi) do {                                                             \
    const u16* KsB = &Ks[curi][0];                                                  \
    const u16* VsB = &Vs[curi][0];                                                  \
    f32x16 sa0 = z16, sa1 = z16;                                                    \
    _Pragma("unroll")                                                               \
    for (int ks = 0; ks < 4; ks++) {                                                \
      const int g0 = ((ks * 2 + hi) ^ (l31 & 7)) * 8;                               \
      bf16x8 kf0 = *(const bf16x8*)&KsB[l31 * 64 + g0];                             \
      bf16x8 kf1 = *(const bf16x8*)&KsB[(32 + l31) * 64 + g0];                      \
      sa0 = __builtin_amdgcn_mfma_f32_32x32x16_bf16(kf0, qf[ks], sa0, 0, 0, 0);     \
      sa1 = __builtin_amdgcn_mfma_f32_32x32x16_bf16(kf1, qf[ks], sa1, 0, 0, 0);     \
    }                                                                               \
    SOFTMAX_BLK(sa0);                                                               \
    PVSTEP(VsB, 0, 0);                                                              \
    PVSTEP(VsB, 1, 1);                                                              \
    SOFTMAX_BLK(sa1);                                                               \
    PVSTEP(VsB, 0, 2);                                                              \
    PVSTEP(VsB, 1, 3);                                                              \
  } while (0)

  constexpr int NKB = SEQ / 64;
  STAGE(0, 0);
  for (int kb = 0; kb < NKB - 1; kb++) {
    const int cur = kb & 1;
    STAGE(kb + 1, cur ^ 1);
    WAITCNT_VM(4);
    BARRIER_FENCED();
    BODY(cur);
    BARRIER_FENCED();
  }
  WAITCNT_VM(0);
  BARRIER_FENCED();
  BODY((NKB - 1) & 1);

  float ls = ls2.x + ls2.y;
  ls += __shfl_xor(ls, 32);
  float inv = 1.0f / ls;

  u16* crow = ctx + ((size_t)(b * SEQ + qrow)) * DM + h * DK;

#define STORE_BLK(OT, DKB) do {                                                     \
    _Pragma("unroll")                                                               \
    for (int t = 0; t < 4; t++) {                                                   \
      uint2 pr;                                                                     \
      pr.x = pk2(OT[4 * t + 0] * inv, OT[4 * t + 1] * inv);                         \
      pr.y = pk2(OT[4 * t + 2] * inv, OT[4 * t + 3] * inv);                         \
      *(uint2*)&crow[(DKB) * 32 + t * 8 + hi * 4] = pr;                             \
    }                                                                               \
  } while (0)

  STORE_BLK(ot0, 0);
  STORE_BLK(ot1, 1);

#undef STAGE
#undef SOFTMAX_BLK
#undef PVSTEP
#undef BODY
#undef STORE_BLK
}

extern "C" void kernel_launch(void* const* d_in, const int* in_sizes, int n_in,
                              void* d_out, int out_size, void* d_ws, size_t ws_size,
                              hipStream_t stream)
{
  const float* q  = (const float*)d_in[0];
  const float* k  = (const float*)d_in[1];
  const float* v  = (const float*)d_in[2];
  const float* Wq = (const float*)d_in[3];
  const float* bq = (const float*)d_in[4];
  const float* Wk = (const float*)d_in[5];
  const float* bk = (const float*)d_in[6];
  const float* Wv = (const float*)d_in[7];
  const float* bv = (const float*)d_in[8];
  const float* Wo = (const float*)d_in[9];
  const float* bo = (const float*)d_in[10];

  const size_t SZ_IN  = (size_t)MTOT * DM;
  const size_t SZ_W   = (size_t)DM * DM;
  const size_t NEED_FUSED = (3 * SZ_IN + 3 * SZ_W + SZ_W + 3 * SZ_IN) * 2;  // 104 MiB

  dim3 cblk(256);
  dim3 gblk(512);
  dim3 ggq(12, 32);    // QKV fused: 3 segs x 4 n-tiles (BN=256), 32 m-tiles
  dim3 ggq1(4, 32);    // QKV split: one seg
  dim3 ggo(8, 32);     // O-proj: BN=128 -> 8 n-tiles, 256 blocks (exact CU fit)

  if (ws_size >= NEED_FUSED) {
    u16* in_c  = (u16*)d_ws;
    u16* w3    = in_c + 3 * SZ_IN;
    u16* wo_c  = w3   + 3 * SZ_W;
    u16* q_ws  = wo_c + SZ_W;
    u16* k_ws  = q_ws + SZ_IN;
    u16* vt_ws = k_ws + SZ_IN;
    u16* ctx   = in_c;

    cast_all<<<14336, cblk, 0, stream>>>(q, k, v, Wq, Wk, Wv, Wo, in_c, w3, wo_c);
    gemm_k<0><<<ggq, gblk, 0, stream>>>(in_c, in_c + SZ_IN, in_c + 2 * SZ_IN, w3,
                                        bq, bk, bv, q_ws, k_ws, vt_ws, nullptr, 0);
    attn3<<<dim3(BATCH * NH, SEQ / 128), cblk, 0, stream>>>(q_ws, k_ws, vt_ws, ctx);
    gemm_k<1><<<ggo, gblk, 0, stream>>>(ctx, ctx, ctx, wo_c,
                                        bo, bo, bo, nullptr, nullptr, nullptr,
                                        (float*)d_out, 0);
  } else {
    u16* in_c  = (u16*)d_ws;
    u16* w3    = in_c + SZ_IN;
    u16* wo_c  = w3   + 3 * SZ_W;
    u16* q_ws  = wo_c + SZ_W;
    u16* k_ws  = q_ws + SZ_IN;
    u16* vt_ws = k_ws + SZ_IN;
    u16* ctx   = in_c;

    const int NA8 = MTOT * DM / 8;
    cast_w<<<2048, cblk, 0, stream>>>(Wq, Wk, Wv, Wo, w3, wo_c);
    cast_bf16<<<NA8 / 256, cblk, 0, stream>>>(q, in_c, NA8);
    gemm_k<0><<<ggq1, gblk, 0, stream>>>(in_c, in_c, in_c, w3, bq, bk, bv,
                                         q_ws, k_ws, vt_ws, nullptr, 0);
    cast_bf16<<<NA8 / 256, cblk, 0, stream>>>(k, in_c, NA8);
    gemm_k<0><<<ggq1, gblk, 0, stream>>>(in_c, in_c, in_c, w3, bq, bk, bv,
                                         q_ws, k_ws, vt_ws, nullptr, 1);
    cast_bf16<<<NA8 / 256, cblk, 0, stream>>>(v, in_c, NA8);
    gemm_k<0><<<ggq1, gblk, 0, stream>>>(in_c, in_c, in_c, w3, bq, bk, bv,
                                         q_ws, k_ws, vt_ws, nullptr, 2);
    attn3<<<dim3(BATCH * NH, SEQ / 128), cblk, 0, stream>>>(q_ws, k_ws, vt_ws, ctx);
    gemm_k<1><<<ggo, gblk, 0, stream>>>(ctx, ctx, ctx, wo_c,
                                        bo, bo, bo, nullptr, nullptr, nullptr,
                                        (float*)d_out, 0);
  }
}

// Round 6
// 370.430 us; speedup vs baseline: 1.0437x; 1.0437x over previous
//
#include <hip/hip_runtime.h>
#include <math.h>

typedef unsigned short u16;
typedef unsigned int   u32;
typedef float f32x4  __attribute__((ext_vector_type(4)));
typedef float f32x16 __attribute__((ext_vector_type(16)));
typedef __bf16 bf16x8 __attribute__((ext_vector_type(8)));
typedef __bf16 bf16x2 __attribute__((ext_vector_type(2)));

#define SEQ   2048
#define BATCH 4
#define NH    16
#define DK    64
#define DM    1024
#define MTOT  (SEQ*BATCH)   /* 8192 rows */
#define SCL_QK 0.18033688011116016f   /* log2(e)/sqrt(64), folded into Q proj */

#if __has_builtin(__builtin_amdgcn_exp2f)
#define EXP2(x) __builtin_amdgcn_exp2f(x)
#else
#define EXP2(x) exp2f(x)
#endif

#define WAITCNT_VM(N) asm volatile("s_waitcnt vmcnt(" #N ")" ::: "memory")
#define WAITCNT_LGKM0() asm volatile("s_waitcnt lgkmcnt(0)" ::: "memory")
#define BARRIER_FENCED() do {                                  \
    asm volatile("" ::: "memory");                             \
    __builtin_amdgcn_s_barrier();                              \
    asm volatile("" ::: "memory");                             \
  } while (0)

template<int N> static __device__ __forceinline__ void vm_wait() {
  if constexpr (N == 0)      asm volatile("s_waitcnt vmcnt(0)" ::: "memory");
  else if constexpr (N == 2) asm volatile("s_waitcnt vmcnt(2)" ::: "memory");
  else if constexpr (N == 4) asm volatile("s_waitcnt vmcnt(4)" ::: "memory");
  else if constexpr (N == 6) asm volatile("s_waitcnt vmcnt(6)" ::: "memory");
  else static_assert(N == 0, "unsupported vmcnt");
}

static __device__ __forceinline__ u16 f2bf(float f) {
  __bf16 h = (__bf16)f;
  return __builtin_bit_cast(u16, h);
}
static __device__ __forceinline__ u32 pk2(float a, float b) {
  bf16x2 t = {(__bf16)a, (__bf16)b};          // -> v_cvt_pk_bf16_f32
  return __builtin_bit_cast(u32, t);
}

typedef __attribute__((address_space(1))) const void g1_t;
typedef __attribute__((address_space(3))) void l3_t;
static __device__ __forceinline__ void gload16(const void* g, void* l) {
  __builtin_amdgcn_global_load_lds((g1_t*)g, (l3_t*)l, 16, 0, 0);
}

static __device__ __forceinline__ void cast8(const float* __restrict__ src,
                                             u16* __restrict__ dst, int i) {
  float4 a = ((const float4*)src)[2 * i];
  float4 b = ((const float4*)src)[2 * i + 1];
  uint4 r;
  r.x = pk2(a.x, a.y); r.y = pk2(a.z, a.w);
  r.z = pk2(b.x, b.y); r.w = pk2(b.z, b.w);
  ((uint4*)dst)[i] = r;
}

// single-tensor cast (split fallback path)
__global__ __launch_bounds__(256)
void cast_bf16(const float* __restrict__ src, u16* __restrict__ dst, int n8) {
  int i = blockIdx.x * 256 + threadIdx.x;
  if (i < n8) cast8(src, dst, i);
}

// weights-only cast: Wq,Wk,Wv -> w3 [3*DM,DM]; Wo -> wo_c. 2048 blocks.
__global__ __launch_bounds__(256)
void cast_w(const float* __restrict__ Wq, const float* __restrict__ Wk,
            const float* __restrict__ Wv, const float* __restrict__ Wo,
            u16* __restrict__ w3, u16* __restrict__ wo_c) {
  int bid = blockIdx.x;
  int t = bid >> 9, idx = bid & 511;
  const float* src = (t == 0) ? Wq : (t == 1) ? Wk : (t == 2) ? Wv : Wo;
  u16* dst = (t < 3) ? (w3 + (size_t)t * DM * DM) : wo_c;
  cast8(src, dst, idx * 256 + threadIdx.x);
}

// ---------------------------------------------------------------------------
// Projection GEMM (proven round-2/4 2-phase 128x128 core, 256 thr, 4 blk/CU,
// counted vmcnt, XCD swizzle) + NEW: AF32 mode fuses the f32->bf16 input cast
// into A-staging (reg-stage: 2xfloat4 load -> cvt_pk -> ds_write_b128), so the
// standalone cast_all pass (~168 MB traffic) disappears.
//
// AF32 vmcnt ledger (A = 4 reg loads, W = 2 gload_lds, per iter, issued A then W):
//   iter kt: loadA(kt+1)[4] ; gloadW(kt+1)[2]          -> outstanding W(kt)2 + 6 = 8
//            vmcnt(6)  retires W(kt)   (A,W of kt+1 stay in flight)
//            barrier ; compute(cur) [ds_read+MFMA]
//            vmcnt(2)  retires A(kt+1) reg loads
//            cvt+ds_write As[cur^1] ; lgkmcnt(0) ; barrier
// Buffer liveness: writes to cur^1 land between the two barriers of iter kt;
// last reader of cur^1 was compute(kt-1), before iter kt-1's trailing barrier.
// Never vmcnt(0) in the main loop.
// OGEMM=0: seg picks {Q,K,V}; A layout [SEQ,BATCH,DM] (f32 if AF32 else bf16);
//          epilogue: seg0 -> o0 [b,h,s,dk]*SCL_QK; seg1 -> o1; seg2 -> o2 [b,h,dk,s]
// OGEMM=1: A = ctx row-major bf16 [M,DM], W = wo_c, out f32 o3 [(s*B+b)*DM+n]
template<int OGEMM, int AF32>
__global__ __launch_bounds__(256, 4)
void gemm_k(const void* __restrict__ a0v, const void* __restrict__ a1v,
            const void* __restrict__ a2v, const u16* __restrict__ w3,
            const float* __restrict__ b0, const float* __restrict__ b1,
            const float* __restrict__ b2,
            u16* __restrict__ o0, u16* __restrict__ o1, u16* __restrict__ o2,
            float* __restrict__ o3, int seg_base)
{
  constexpr int BM = 128, BN = 128, BK = 32;
  __shared__ u16 As[2][BM * BK];
  __shared__ u16 Bs[2][BN * BK];

  // T1 chunked XCD swizzle (nwg % 8 == 0 -> bijective)
  const int nwg = gridDim.x * gridDim.y;
  const int bid = blockIdx.y * gridDim.x + blockIdx.x;
  const int swz = (bid & 7) * (nwg >> 3) + (bid >> 3);
  const int bx  = swz % gridDim.x;
  const int by  = swz / gridDim.x;

  const int seg = OGEMM ? 0 : (seg_base + (int)(bx >> 3));
  const int n0  = OGEMM ? bx * BN : (bx & 7) * BN;
  const int m0  = by * BM;
  const void* Av = OGEMM ? a0v : (seg == 0 ? a0v : seg == 1 ? a1v : a2v);
  const u16*   A16 = (const u16*)Av;
  const float* A32 = (const float*)Av;
  const u16* W = OGEMM ? w3 : (w3 + (size_t)seg * DM * DM);
  const float* bias = OGEMM ? b0 : (seg == 0 ? b0 : seg == 1 ? b1 : b2);

  const int tid  = threadIdx.x;
  const int w    = tid >> 6;
  const int lane = tid & 63;
  const int quad = lane >> 4;
  const int l15  = lane & 15;
  const int wm = (w >> 1) * 64;
  const int wn = (w & 1) * 64;

  size_t aoff[2], woff[2];
  for (int p = 0; p < 2; p++) {
    int row = w * 32 + p * 16 + (lane >> 2);
    int gm = m0 + row;
    if (OGEMM) {
      aoff[p] = (size_t)gm * DM + (lane & 3) * 8;
    } else {
      int bb = gm >> 11, s = gm & (SEQ - 1);
      aoff[p] = (size_t)(s * BATCH + bb) * DM + (lane & 3) * 8;
    }
    woff[p] = (size_t)(n0 + row) * DM + (lane & 3) * 8;
  }

  f32x4 acc[4][4];
  for (int i = 0; i < 4; i++)
    for (int j = 0; j < 4; j++)
      acc[i][j] = (f32x4){0.f, 0.f, 0.f, 0.f};

  float4 a_nx[2][2];   // AF32 in-flight A registers

  auto loadA32 = [&](int kt) {
#pragma unroll
    for (int p = 0; p < 2; p++) {
      const float* s = A32 + aoff[p] + kt * BK;
      a_nx[p][0] = *(const float4*)s;
      a_nx[p][1] = *(const float4*)(s + 4);
    }
  };
  auto writeA32 = [&](int bufi) {
#pragma unroll
    for (int p = 0; p < 2; p++) {
      uint4 r;
      r.x = pk2(a_nx[p][0].x, a_nx[p][0].y);
      r.y = pk2(a_nx[p][0].z, a_nx[p][0].w);
      r.z = pk2(a_nx[p][1].x, a_nx[p][1].y);
      r.w = pk2(a_nx[p][1].z, a_nx[p][1].w);
      *(uint4*)&As[bufi][(w * 32 + p * 16 + (lane >> 2)) * BK + (lane & 3) * 8] = r;
    }
  };
  auto stageA16 = [&](int kt, int bufi) {
#pragma unroll
    for (int p = 0; p < 2; p++)
      gload16(A16 + aoff[p] + kt * BK, &As[bufi][(w * 32 + p * 16) * BK]);
  };
  auto stageW = [&](int kt, int bufi) {
#pragma unroll
    for (int p = 0; p < 2; p++)
      gload16(W + woff[p] + kt * BK, &Bs[bufi][(w * 32 + p * 16) * BK]);
  };
  auto compute = [&](int cur) {
    bf16x8 af[4], bfr[4];
#pragma unroll
    for (int i = 0; i < 4; i++)
      af[i] = *(const bf16x8*)&As[cur][(wm + i * 16 + l15) * BK + quad * 8];
#pragma unroll
    for (int j = 0; j < 4; j++)
      bfr[j] = *(const bf16x8*)&Bs[cur][(wn + j * 16 + l15) * BK + quad * 8];
#pragma unroll
    for (int i = 0; i < 4; i++)
#pragma unroll
      for (int j = 0; j < 4; j++)
        acc[i][j] = __builtin_amdgcn_mfma_f32_16x16x32_bf16(af[i], bfr[j], acc[i][j], 0, 0, 0);
  };

  constexpr int NKT = DM / BK;   // 32
  if constexpr (AF32) {
    // prologue: A(0) regs + W(0) gload; publish As[0]
    loadA32(0);
    stageW(0, 0);
    vm_wait<2>();                // A(0) ready, W(0) in flight
    writeA32(0);
    WAITCNT_LGKM0();
    for (int kt = 0; kt < NKT - 1; kt++) {
      const int cur = kt & 1;
      loadA32(kt + 1);
      stageW(kt + 1, cur ^ 1);
      vm_wait<6>();              // W(kt) retired; kt+1's 6 ops in flight
      BARRIER_FENCED();
      compute(cur);
      vm_wait<2>();              // A(kt+1) regs ready (W(kt+1) in flight)
      writeA32(cur ^ 1);
      WAITCNT_LGKM0();
      BARRIER_FENCED();
    }
    vm_wait<0>();                // final: W(NKT-1)
    BARRIER_FENCED();
    compute((NKT - 1) & 1);
  } else {
    stageA16(0, 0);
    stageW(0, 0);
    for (int kt = 0; kt < NKT - 1; kt++) {
      const int cur = kt & 1;
      stageA16(kt + 1, cur ^ 1);
      stageW(kt + 1, cur ^ 1);
      vm_wait<4>();              // tile kt retired; kt+1's 4 loads in flight
      BARRIER_FENCED();
      compute(cur);
      BARRIER_FENCED();
    }
    vm_wait<0>();
    BARRIER_FENCED();
    compute((NKT - 1) & 1);
  }

  // C/D layout: col(n) = lane&15, row(m) = quad*4 + reg
  for (int j = 0; j < 4; j++) {
    int gn = n0 + wn + j * 16 + l15;
    float bv = bias[gn];
    int h = gn >> 6, dk = gn & 63;
    for (int i = 0; i < 4; i++) {
      int gmb = m0 + wm + i * 16 + quad * 4;
      for (int r = 0; r < 4; r++) {
        int gm = gmb + r;
        float val = acc[i][j][r] + bv;
        int bb = gm >> 11, s = gm & (SEQ - 1);
        if (OGEMM) {
          o3[(size_t)(s * BATCH + bb) * DM + gn] = val;
        } else if (seg == 0) {
          o0[((size_t)(bb * NH + h) * SEQ + s) * DK + dk] = f2bf(val * SCL_QK);
        } else if (seg == 1) {
          o1[((size_t)(bb * NH + h) * SEQ + s) * DK + dk] = f2bf(val);
        } else {
          o2[((size_t)(bb * NH + h) * DK + dk) * SEQ + s] = f2bf(val);
        }
      }
    }
  }
}

// ---------------------------------------------------------------------------
// Flash attention (round-4 version, unchanged): 32x32x16 MFMA, lane^32 P
// exchange, 2-buffer depth-1 K/V pipeline with counted vmcnt.
__global__ __launch_bounds__(256, 4)
void attn3(const u16* __restrict__ Q, const u16* __restrict__ K,
           const u16* __restrict__ VT, u16* __restrict__ ctx)
{
  __shared__ u16 Ks[2][64 * 64];
  __shared__ u16 Vs[2][64 * 64];

  const int bh = blockIdx.x;
  const int qt = blockIdx.y;
  const int b  = bh >> 4, h = bh & 15;
  const int tid  = threadIdx.x;
  const int w    = tid >> 6;
  const int lane = tid & 63;
  const int l31  = lane & 31;
  const int hi   = lane >> 5;

  const u16* Qb = Q  + (size_t)bh * SEQ * DK;
  const u16* Kb = K  + (size_t)bh * SEQ * DK;
  const u16* Vb = VT + (size_t)bh * DK * SEQ;

  const int qbase = qt * 128 + w * 32;
  const int qrow  = qbase + l31;

  bf16x8 qf[4];
#pragma unroll
  for (int ks = 0; ks < 4; ks++)
    qf[ks] = *(const bf16x8*)&Qb[(size_t)qrow * DK + ks * 16 + hi * 8];

  const int r0 = tid >> 3;
  const int sw = (tid & 7) ^ (r0 & 7);

#define STAGE(kbb, bufi) do {                                                       \
    _Pragma("unroll")                                                               \
    for (int p = 0; p < 2; p++) {                                                   \
      int row = p * 32 + r0;                                                        \
      gload16(&Kb[(size_t)((kbb) * 64 + row) * DK + sw * 8],                        \
              &Ks[bufi][(p * 32 + w * 8) * 64]);                                    \
      gload16(&Vb[(size_t)row * SEQ + (kbb) * 64 + sw * 8],                         \
              &Vs[bufi][(p * 32 + w * 8) * 64]);                                    \
    }                                                                               \
  } while (0)

  f32x16 z16;
#pragma unroll
  for (int i = 0; i < 16; i++) z16[i] = 0.f;

  f32x16 ot0 = z16, ot1 = z16;
  float2 ls2 = {0.f, 0.f};

  u32 wp[8];

#define SOFTMAX_BLK(SA) do {                                                        \
    _Pragma("unroll")                                                               \
    for (int g = 0; g < 8; g++) {                                                   \
      float pa = EXP2(SA[2 * g]);                                                   \
      float pb = EXP2(SA[2 * g + 1]);                                               \
      ls2.x += pa; ls2.y += pb;                                                     \
      wp[g] = pk2(pa, pb);                                                          \
    }                                                                               \
  } while (0)

#define PVSTEP(VsB, KSB, KSL) do {                                                  \
    u32 a0 = wp[(KSB) * 4 + 0], a1 = wp[(KSB) * 4 + 1];                             \
    u32 a2 = wp[(KSB) * 4 + 2], a3 = wp[(KSB) * 4 + 3];                             \
    u32 s0 = hi ? a0 : a2, s1 = hi ? a1 : a3;                                       \
    u32 x0 = (u32)__shfl_xor((int)s0, 32);                                          \
    u32 x1 = (u32)__shfl_xor((int)s1, 32);                                          \
    uint4 pw;                                                                       \
    pw.x = hi ? x0 : a0; pw.y = hi ? x1 : a1;                                       \
    pw.z = hi ? a2 : x0; pw.w = hi ? a3 : x1;                                       \
    bf16x8 pf = __builtin_bit_cast(bf16x8, pw);                                     \
    const int gg = (((KSL) * 2 + hi) ^ (l31 & 7)) * 8;                              \
    bf16x8 vf0 = *(const bf16x8*)&VsB[l31 * 64 + gg];                               \
    bf16x8 vf1 = *(const bf16x8*)&VsB[(32 + l31) * 64 + gg];                        \
    ot0 = __builtin_amdgcn_mfma_f32_32x32x16_bf16(vf0, pf, ot0, 0, 0, 0);           \
    ot1 = __builtin_amdgcn_mfma_f32_32x32x16_bf16(vf1, pf, ot1, 0, 0, 0);           \
  } while (0)

#define BODY(curi) do {                                                             \
    const u16* KsB = &Ks[curi][0];                                                  \
    const u16* VsB = &Vs[curi][0];                                                  \
    f32x16 sa0 = z16, sa1 = z16;                                                    \
    _Pragma("unroll")                                                               \
    for (int ks = 0; ks < 4; ks++) {                                                \
      const int g0 = ((ks * 2 + hi) ^ (l31 & 7)) * 8;                               \
      bf16x8 kf0 = *(const bf16x8*)&KsB[l31 * 64 + g0];                             \
      bf16x8 kf1 = *(const bf16x8*)&KsB[(32 + l31) * 64 + g0];                      \
      sa0 = __builtin_amdgcn_mfma_f32_32x32x16_bf16(kf0, qf[ks], sa0, 0, 0, 0);     \
      sa1 = __builtin_amdgcn_mfma_f32_32x32x16_bf16(kf1, qf[ks], sa1, 0, 0, 0);     \
    }                                                                               \
    SOFTMAX_BLK(sa0);                                                               \
    PVSTEP(VsB, 0, 0);                                                              \
    PVSTEP(VsB, 1, 1);                                                              \
    SOFTMAX_BLK(sa1);                                                               \
    PVSTEP(VsB, 0, 2);                                                              \
    PVSTEP(VsB, 1, 3);                                                              \
  } while (0)

  constexpr int NKB = SEQ / 64;
  STAGE(0, 0);
  for (int kb = 0; kb < NKB - 1; kb++) {
    const int cur = kb & 1;
    STAGE(kb + 1, cur ^ 1);
    WAITCNT_VM(4);
    BARRIER_FENCED();
    BODY(cur);
    BARRIER_FENCED();
  }
  WAITCNT_VM(0);
  BARRIER_FENCED();
  BODY((NKB - 1) & 1);

  float ls = ls2.x + ls2.y;
  ls += __shfl_xor(ls, 32);
  float inv = 1.0f / ls;

  u16* crow = ctx + ((size_t)(b * SEQ + qrow)) * DM + h * DK;

#define STORE_BLK(OT, DKB) do {                                                     \
    _Pragma("unroll")                                                               \
    for (int t = 0; t < 4; t++) {                                                   \
      uint2 pr;                                                                     \
      pr.x = pk2(OT[4 * t + 0] * inv, OT[4 * t + 1] * inv);                         \
      pr.y = pk2(OT[4 * t + 2] * inv, OT[4 * t + 3] * inv);                         \
      *(uint2*)&crow[(DKB) * 32 + t * 8 + hi * 4] = pr;                             \
    }                                                                               \
  } while (0)

  STORE_BLK(ot0, 0);
  STORE_BLK(ot1, 1);

#undef STAGE
#undef SOFTMAX_BLK
#undef PVSTEP
#undef BODY
#undef STORE_BLK
}

extern "C" void kernel_launch(void* const* d_in, const int* in_sizes, int n_in,
                              void* d_out, int out_size, void* d_ws, size_t ws_size,
                              hipStream_t stream)
{
  const float* q  = (const float*)d_in[0];
  const float* k  = (const float*)d_in[1];
  const float* v  = (const float*)d_in[2];
  const float* Wq = (const float*)d_in[3];
  const float* bq = (const float*)d_in[4];
  const float* Wk = (const float*)d_in[5];
  const float* bk = (const float*)d_in[6];
  const float* Wv = (const float*)d_in[7];
  const float* bv = (const float*)d_in[8];
  const float* Wo = (const float*)d_in[9];
  const float* bo = (const float*)d_in[10];

  const size_t SZ_IN  = (size_t)MTOT * DM;
  const size_t SZ_W   = (size_t)DM * DM;
  // fused-cast path: w3(3W) + wo(1W) + q/k/vt ws(3IN) + ctx(1IN), bf16
  const size_t NEED_FUSED = (4 * SZ_W + 4 * SZ_IN) * 2;   // ~75.5 MiB

  dim3 cblk(256);
  dim3 ggq(24, 64);   // QKV fused: 3 segs x 8 n-tiles (BN=128), 64 m-tiles
  dim3 ggs(8, 64);
  dim3 agrid(BATCH * NH, SEQ / 128);

  if (ws_size >= NEED_FUSED) {
    u16* w3    = (u16*)d_ws;
    u16* wo_c  = w3    + 3 * SZ_W;
    u16* q_ws  = wo_c  + SZ_W;
    u16* k_ws  = q_ws  + SZ_IN;
    u16* vt_ws = k_ws  + SZ_IN;     // [b,h,dk,s]
    u16* ctx   = vt_ws + SZ_IN;

    cast_w<<<2048, cblk, 0, stream>>>(Wq, Wk, Wv, Wo, w3, wo_c);
    gemm_k<0, 1><<<ggq, cblk, 0, stream>>>(q, k, v, w3,
                                           bq, bk, bv, q_ws, k_ws, vt_ws,
                                           nullptr, 0);
    attn3<<<agrid, cblk, 0, stream>>>(q_ws, k_ws, vt_ws, ctx);
    gemm_k<1, 0><<<ggs, cblk, 0, stream>>>(ctx, ctx, ctx, wo_c,
                                           bo, bo, bo, nullptr, nullptr, nullptr,
                                           (float*)d_out, 0);
  } else {
    u16* in_c  = (u16*)d_ws;
    u16* w3    = in_c + SZ_IN;
    u16* wo_c  = w3   + 3 * SZ_W;
    u16* q_ws  = wo_c + SZ_W;
    u16* k_ws  = q_ws + SZ_IN;
    u16* vt_ws = k_ws + SZ_IN;
    u16* ctx   = in_c;

    const int NA8 = MTOT * DM / 8;
    cast_w<<<2048, cblk, 0, stream>>>(Wq, Wk, Wv, Wo, w3, wo_c);
    cast_bf16<<<NA8 / 256, cblk, 0, stream>>>(q, in_c, NA8);
    gemm_k<0, 0><<<ggs, cblk, 0, stream>>>(in_c, in_c, in_c, w3, bq, bk, bv,
                                           q_ws, k_ws, vt_ws, nullptr, 0);
    cast_bf16<<<NA8 / 256, cblk, 0, stream>>>(k, in_c, NA8);
    gemm_k<0, 0><<<ggs, cblk, 0, stream>>>(in_c, in_c, in_c, w3, bq, bk, bv,
                                           q_ws, k_ws, vt_ws, nullptr, 1);
    cast_bf16<<<NA8 / 256, cblk, 0, stream>>>(v, in_c, NA8);
    gemm_k<0, 0><<<ggs, cblk, 0, stream>>>(in_c, in_c, in_c, w3, bq, bk, bv,
                                           q_ws, k_ws, vt_ws, nullptr, 2);
    attn3<<<agrid, cblk, 0, stream>>>(q_ws, k_ws, vt_ws, ctx);
    gemm_k<1, 0><<<ggs, cblk, 0, stream>>>(ctx, ctx, ctx, wo_c,
                                           bo, bo, bo, nullptr, nullptr, nullptr,
                                           (float*)d_out, 0);
  }
}

// Round 7
// 369.367 us; speedup vs baseline: 1.0467x; 1.0029x over previous
//
#include <hip/hip_runtime.h>
#include <math.h>

typedef unsigned short u16;
typedef unsigned int   u32;
typedef unsigned int   u32x2 __attribute__((ext_vector_type(2)));
typedef float f32x4  __attribute__((ext_vector_type(4)));
typedef float f32x16 __attribute__((ext_vector_type(16)));
typedef __bf16 bf16x8 __attribute__((ext_vector_type(8)));
typedef __bf16 bf16x2 __attribute__((ext_vector_type(2)));

#define SEQ   2048
#define BATCH 4
#define NH    16
#define DK    64
#define DM    1024
#define MTOT  (SEQ*BATCH)   /* 8192 rows */
#define SCL_QK 0.18033688011116016f   /* log2(e)/sqrt(64), folded into Q proj */

#if __has_builtin(__builtin_amdgcn_exp2f)
#define EXP2(x) __builtin_amdgcn_exp2f(x)
#else
#define EXP2(x) exp2f(x)
#endif

// in-place half-wave swap: d0.hi <-> d1.lo  (v_permlane32_swap_b32)
#if __has_builtin(__builtin_amdgcn_permlane32_swap)
#define PLSWAP(X, Y) do {                                          \
    u32x2 _r = __builtin_amdgcn_permlane32_swap((X), (Y), false, false); \
    (X) = _r.x; (Y) = _r.y;                                        \
  } while (0)
#else
#define PLSWAP(X, Y) \
  asm("v_permlane32_swap_b32 %0, %1" : "+v"(X), "+v"(Y))
#endif

#define WAITCNT_VM(N) asm volatile("s_waitcnt vmcnt(" #N ")" ::: "memory")
#define BARRIER_FENCED() do {                                  \
    asm volatile("" ::: "memory");                             \
    __builtin_amdgcn_s_barrier();                              \
    asm volatile("" ::: "memory");                             \
  } while (0)

static __device__ __forceinline__ u16 f2bf(float f) {
  __bf16 h = (__bf16)f;
  return __builtin_bit_cast(u16, h);
}
static __device__ __forceinline__ u32 pk2(float a, float b) {
  bf16x2 t = {(__bf16)a, (__bf16)b};          // -> v_cvt_pk_bf16_f32
  return __builtin_bit_cast(u32, t);
}

typedef __attribute__((address_space(1))) const void g1_t;
typedef __attribute__((address_space(3))) void l3_t;
static __device__ __forceinline__ void gload16(const void* g, void* l) {
  __builtin_amdgcn_global_load_lds((g1_t*)g, (l3_t*)l, 16, 0, 0);
}

static __device__ __forceinline__ void cast8(const float* __restrict__ src,
                                             u16* __restrict__ dst, int i) {
  float4 a = ((const float4*)src)[2 * i];
  float4 b = ((const float4*)src)[2 * i + 1];
  uint4 r;
  r.x = pk2(a.x, a.y); r.y = pk2(a.z, a.w);
  r.z = pk2(b.x, b.y); r.w = pk2(b.z, b.w);
  ((uint4*)dst)[i] = r;
}

// single-tensor cast (split path)
__global__ __launch_bounds__(256)
void cast_bf16(const float* __restrict__ src, u16* __restrict__ dst, int n8) {
  int i = blockIdx.x * 256 + threadIdx.x;
  if (i < n8) cast8(src, dst, i);
}

// weights-only fused cast: Wq,Wk,Wv -> w3 [3*DM,DM]; Wo -> wo_c. 2048 blocks.
__global__ __launch_bounds__(256)
void cast_w(const float* __restrict__ Wq, const float* __restrict__ Wk,
            const float* __restrict__ Wv, const float* __restrict__ Wo,
            u16* __restrict__ w3, u16* __restrict__ wo_c) {
  int bid = blockIdx.x;
  int t = bid >> 9, idx = bid & 511;
  const float* src = (t == 0) ? Wq : (t == 1) ? Wk : (t == 2) ? Wv : Wo;
  u16* dst = (t < 3) ? (w3 + (size_t)t * DM * DM) : wo_c;
  cast8(src, dst, idx * 256 + threadIdx.x);
}

// everything-cast: q,k,v (4096 blocks each) + 4 weights (512 each) = 14336 blocks.
__global__ __launch_bounds__(256)
void cast_all(const float* __restrict__ q, const float* __restrict__ k,
              const float* __restrict__ v,
              const float* __restrict__ Wq, const float* __restrict__ Wk,
              const float* __restrict__ Wv, const float* __restrict__ Wo,
              u16* __restrict__ in_c, u16* __restrict__ w3, u16* __restrict__ wo_c) {
  int bid = blockIdx.x;
  const float* src; u16* dst; int idx;
  if (bid < 12288) {
    int t = bid >> 12; idx = bid & 4095;
    src = (t == 0) ? q : (t == 1) ? k : v;
    dst = in_c + (size_t)t * MTOT * DM;
  } else {
    int wb = bid - 12288;
    int t = wb >> 9; idx = wb & 511;
    src = (t == 0) ? Wq : (t == 1) ? Wk : (t == 2) ? Wv : Wo;
    dst = (t < 3) ? (w3 + (size_t)t * DM * DM) : wo_c;
  }
  cast8(src, dst, idx * 256 + threadIdx.x);
}

// Projection GEMM — round-4 proven core (2-phase, counted vmcnt, XCD swizzle)
// with ONE change: __launch_bounds__(256,5) -> 5 blocks/CU (LDS 5x32KB = 160KB
// exact fit; VGPR 56 << 102 cap). The 2-phase loop is latency-bound; depth-2
// pipelines failed twice (R3 occupancy loss, R4 null) -> add TLP instead.
// OGEMM=0: seg = seg_base + bx>>3 picks {Q,K,V}: A in [SEQ,BATCH,DM] order, W = w3 seg,
//          epilogue: seg0 -> o0 [b,h,s,dk] *SCL_QK; seg1 -> o1 [b,h,s,dk]; seg2 -> o2 [b,h,dk,s]
// OGEMM=1: A = ctx row-major [M,DM], W = w3(=wo_c), out f32 o3 [(s*B+b)*DM+n]
template<int OGEMM>
__global__ __launch_bounds__(256, 5)
void gemm_k(const u16* __restrict__ a0, const u16* __restrict__ a1,
            const u16* __restrict__ a2, const u16* __restrict__ w3,
            const float* __restrict__ b0, const float* __restrict__ b1,
            const float* __restrict__ b2,
            u16* __restrict__ o0, u16* __restrict__ o1, u16* __restrict__ o2,
            float* __restrict__ o3, int seg_base)
{
  constexpr int BM = 128, BN = 128, BK = 32;
  __shared__ u16 As[2][BM * BK];
  __shared__ u16 Bs[2][BN * BK];

  // T1 chunked XCD swizzle (nwg % 8 == 0 -> bijective)
  const int nwg = gridDim.x * gridDim.y;
  const int bid = blockIdx.y * gridDim.x + blockIdx.x;
  const int swz = (bid & 7) * (nwg >> 3) + (bid >> 3);
  const int bx  = swz % gridDim.x;
  const int by  = swz / gridDim.x;

  const int seg = OGEMM ? 0 : (seg_base + (int)(bx >> 3));
  const int n0  = OGEMM ? bx * BN : (bx & 7) * BN;
  const int m0  = by * BM;
  const u16* A = OGEMM ? a0 : (seg == 0 ? a0 : seg == 1 ? a1 : a2);
  const u16* W = OGEMM ? w3 : (w3 + (size_t)seg * DM * DM);
  const float* bias = OGEMM ? b0 : (seg == 0 ? b0 : seg == 1 ? b1 : b2);

  const int tid  = threadIdx.x;
  const int w    = tid >> 6;
  const int lane = tid & 63;
  const int quad = lane >> 4;
  const int l15  = lane & 15;
  const int wm = (w >> 1) * 64;
  const int wn = (w & 1) * 64;

  size_t aoff[2], woff[2];
  for (int p = 0; p < 2; p++) {
    int row = w * 32 + p * 16 + (lane >> 2);
    int gm = m0 + row;
    if (OGEMM) {
      aoff[p] = (size_t)gm * DM + (lane & 3) * 8;
    } else {
      int bb = gm >> 11, s = gm & (SEQ - 1);
      aoff[p] = (size_t)(s * BATCH + bb) * DM + (lane & 3) * 8;
    }
    woff[p] = (size_t)(n0 + row) * DM + (lane & 3) * 8;
  }

  f32x4 acc[4][4];
  for (int i = 0; i < 4; i++)
    for (int j = 0; j < 4; j++)
      acc[i][j] = (f32x4){0.f, 0.f, 0.f, 0.f};

  auto stage = [&](int kt, int bufi) {
#pragma unroll
    for (int p = 0; p < 2; p++) {
      gload16(A + aoff[p] + kt * BK, &As[bufi][(w * 32 + p * 16) * BK]);
      gload16(W + woff[p] + kt * BK, &Bs[bufi][(w * 32 + p * 16) * BK]);
    }
  };
  auto compute = [&](int cur) {
    bf16x8 af[4], bfr[4];
#pragma unroll
    for (int i = 0; i < 4; i++)
      af[i] = *(const bf16x8*)&As[cur][(wm + i * 16 + l15) * BK + quad * 8];
#pragma unroll
    for (int j = 0; j < 4; j++)
      bfr[j] = *(const bf16x8*)&Bs[cur][(wn + j * 16 + l15) * BK + quad * 8];
#pragma unroll
    for (int i = 0; i < 4; i++)
#pragma unroll
      for (int j = 0; j < 4; j++)
        acc[i][j] = __builtin_amdgcn_mfma_f32_16x16x32_bf16(af[i], bfr[j], acc[i][j], 0, 0, 0);
  };

  constexpr int NKT = DM / BK;   // 32
  stage(0, 0);
  for (int kt = 0; kt < NKT - 1; kt++) {
    const int cur = kt & 1;
    stage(kt + 1, cur ^ 1);      // issue next tile first
    WAITCNT_VM(4);               // tile kt retired; kt+1's 4 loads in flight
    BARRIER_FENCED();
    compute(cur);
    BARRIER_FENCED();            // readers done before next iter's stage overwrite
  }
  WAITCNT_VM(0);                 // final tile: full drain
  BARRIER_FENCED();
  compute((NKT - 1) & 1);

  // C/D layout: col(n) = lane&15, row(m) = quad*4 + reg
  for (int j = 0; j < 4; j++) {
    int gn = n0 + wn + j * 16 + l15;
    float bv = bias[gn];
    int h = gn >> 6, dk = gn & 63;
    for (int i = 0; i < 4; i++) {
      int gmb = m0 + wm + i * 16 + quad * 4;
      for (int r = 0; r < 4; r++) {
        int gm = gmb + r;
        float val = acc[i][j][r] + bv;
        int bb = gm >> 11, s = gm & (SEQ - 1);
        if (OGEMM) {
          o3[(size_t)(s * BATCH + bb) * DM + gn] = val;
        } else if (seg == 0) {
          o0[((size_t)(bb * NH + h) * SEQ + s) * DK + dk] = f2bf(val * SCL_QK);
        } else if (seg == 1) {
          o1[((size_t)(bb * NH + h) * SEQ + s) * DK + dk] = f2bf(val);
        } else {
          o2[((size_t)(bb * NH + h) * DK + dk) * SEQ + s] = f2bf(val);
        }
      }
    }
  }
}

// ---------------------------------------------------------------------------
// Flash attention (round-4 core) with ONE change: the PVSTEP cross-half
// exchange (2 shuffles + 8 selects) is replaced by 2 in-place
// v_permlane32_swap_b32.
// Derivation (exactness): old code computed, per 64-lane register,
//   pw.x = {a0.lo | a2.lo}   pw.z = {a0.hi | a2.hi}
//   pw.y = {a1.lo | a3.lo}   pw.w = {a1.hi | a3.hi}
// permlane32_swap(d0,d1) swaps d0.hi <-> d1.lo:
//   new d0 = {d0.lo, d1.lo} ; new d1 = {d0.hi, d1.hi}
// so swap(a0,a2) -> (pw.x, pw.z); swap(a1,a3) -> (pw.y, pw.w). Identical.
__global__ __launch_bounds__(256, 4)
void attn3(const u16* __restrict__ Q, const u16* __restrict__ K,
           const u16* __restrict__ VT, u16* __restrict__ ctx)
{
  __shared__ u16 Ks[2][64 * 64];
  __shared__ u16 Vs[2][64 * 64];

  const int bh = blockIdx.x;
  const int qt = blockIdx.y;
  const int b  = bh >> 4, h = bh & 15;
  const int tid  = threadIdx.x;
  const int w    = tid >> 6;
  const int lane = tid & 63;
  const int l31  = lane & 31;
  const int hi   = lane >> 5;

  const u16* Qb = Q  + (size_t)bh * SEQ * DK;
  const u16* Kb = K  + (size_t)bh * SEQ * DK;
  const u16* Vb = VT + (size_t)bh * DK * SEQ;

  const int qbase = qt * 128 + w * 32;
  const int qrow  = qbase + l31;

  bf16x8 qf[4];
#pragma unroll
  for (int ks = 0; ks < 4; ks++)
    qf[ks] = *(const bf16x8*)&Qb[(size_t)qrow * DK + ks * 16 + hi * 8];

  const int r0 = tid >> 3;
  const int sw = (tid & 7) ^ (r0 & 7);

#define STAGE(kbb, bufi) do {                                                       \
    _Pragma("unroll")                                                               \
    for (int p = 0; p < 2; p++) {                                                   \
      int row = p * 32 + r0;                                                        \
      gload16(&Kb[(size_t)((kbb) * 64 + row) * DK + sw * 8],                        \
              &Ks[bufi][(p * 32 + w * 8) * 64]);                                    \
      gload16(&Vb[(size_t)row * SEQ + (kbb) * 64 + sw * 8],                         \
              &Vs[bufi][(p * 32 + w * 8) * 64]);                                    \
    }                                                                               \
  } while (0)

  f32x16 z16;
#pragma unroll
  for (int i = 0; i < 16; i++) z16[i] = 0.f;

  f32x16 ot0 = z16, ot1 = z16;
  float2 ls2 = {0.f, 0.f};

  u32 wp[8];

#define SOFTMAX_BLK(SA) do {                                                        \
    _Pragma("unroll")                                                               \
    for (int g = 0; g < 8; g++) {                                                   \
      float pa = EXP2(SA[2 * g]);                                                   \
      float pb = EXP2(SA[2 * g + 1]);                                               \
      ls2.x += pa; ls2.y += pb;                                                     \
      wp[g] = pk2(pa, pb);                                                          \
    }                                                                               \
  } while (0)

#define PVSTEP(VsB, KSB, KSL) do {                                                  \
    u32 a0 = wp[(KSB) * 4 + 0], a1 = wp[(KSB) * 4 + 1];                             \
    u32 a2 = wp[(KSB) * 4 + 2], a3 = wp[(KSB) * 4 + 3];                             \
    PLSWAP(a0, a2);                                                                 \
    PLSWAP(a1, a3);                                                                 \
    uint4 pw;                                                                       \
    pw.x = a0; pw.y = a1; pw.z = a2; pw.w = a3;                                     \
    bf16x8 pf = __builtin_bit_cast(bf16x8, pw);                                     \
    const int gg = (((KSL) * 2 + hi) ^ (l31 & 7)) * 8;                              \
    bf16x8 vf0 = *(const bf16x8*)&VsB[l31 * 64 + gg];                               \
    bf16x8 vf1 = *(const bf16x8*)&VsB[(32 + l31) * 64 + gg];                        \
    ot0 = __builtin_amdgcn_mfma_f32_32x32x16_bf16(vf0, pf, ot0, 0, 0, 0);           \
    ot1 = __builtin_amdgcn_mfma_f32_32x32x16_bf16(vf1, pf, ot1, 0, 0, 0);           \
  } while (0)

#define BODY(curi) do {                                                             \
    const u16* KsB = &Ks[curi][0];                                                  \
    const u16* VsB = &Vs[curi][0];                                                  \
    f32x16 sa0 = z16, sa1 = z16;                                                    \
    _Pragma("unroll")                                                               \
    for (int ks = 0; ks < 4; ks++) {                                                \
      const int g0 = ((ks * 2 + hi) ^ (l31 & 7)) * 8;                               \
      bf16x8 kf0 = *(const bf16x8*)&KsB[l31 * 64 + g0];                             \
      bf16x8 kf1 = *(const bf16x8*)&KsB[(32 + l31) * 64 + g0];                      \
      sa0 = __builtin_amdgcn_mfma_f32_32x32x16_bf16(kf0, qf[ks], sa0, 0, 0, 0);     \
      sa1 = __builtin_amdgcn_mfma_f32_32x32x16_bf16(kf1, qf[ks], sa1, 0, 0, 0);     \
    }                                                                               \
    SOFTMAX_BLK(sa0);                                                               \
    PVSTEP(VsB, 0, 0);                                                              \
    PVSTEP(VsB, 1, 1);                                                              \
    SOFTMAX_BLK(sa1);                                                               \
    PVSTEP(VsB, 0, 2);                                                              \
    PVSTEP(VsB, 1, 3);                                                              \
  } while (0)

  constexpr int NKB = SEQ / 64;
  STAGE(0, 0);
  for (int kb = 0; kb < NKB - 1; kb++) {
    const int cur = kb & 1;
    STAGE(kb + 1, cur ^ 1);
    WAITCNT_VM(4);
    BARRIER_FENCED();
    BODY(cur);
    BARRIER_FENCED();
  }
  WAITCNT_VM(0);
  BARRIER_FENCED();
  BODY((NKB - 1) & 1);

  float ls = ls2.x + ls2.y;
  ls += __shfl_xor(ls, 32);
  float inv = 1.0f / ls;

  u16* crow = ctx + ((size_t)(b * SEQ + qrow)) * DM + h * DK;

#define STORE_BLK(OT, DKB) do {                                                     \
    _Pragma("unroll")                                                               \
    for (int t = 0; t < 4; t++) {                                                   \
      uint2 pr;                                                                     \
      pr.x = pk2(OT[4 * t + 0] * inv, OT[4 * t + 1] * inv);                         \
      pr.y = pk2(OT[4 * t + 2] * inv, OT[4 * t + 3] * inv);                         \
      *(uint2*)&crow[(DKB) * 32 + t * 8 + hi * 4] = pr;                             \
    }                                                                               \
  } while (0)

  STORE_BLK(ot0, 0);
  STORE_BLK(ot1, 1);

#undef STAGE
#undef SOFTMAX_BLK
#undef PVSTEP
#undef BODY
#undef STORE_BLK
}

extern "C" void kernel_launch(void* const* d_in, const int* in_sizes, int n_in,
                              void* d_out, int out_size, void* d_ws, size_t ws_size,
                              hipStream_t stream)
{
  const float* q  = (const float*)d_in[0];
  const float* k  = (const float*)d_in[1];
  const float* v  = (const float*)d_in[2];
  const float* Wq = (const float*)d_in[3];
  const float* bq = (const float*)d_in[4];
  const float* Wk = (const float*)d_in[5];
  const float* bk = (const float*)d_in[6];
  const float* Wv = (const float*)d_in[7];
  const float* bv = (const float*)d_in[8];
  const float* Wo = (const float*)d_in[9];
  const float* bo = (const float*)d_in[10];

  const size_t SZ_IN  = (size_t)MTOT * DM;
  const size_t SZ_W   = (size_t)DM * DM;
  const size_t NEED_FUSED = (3 * SZ_IN + 3 * SZ_W + SZ_W + 3 * SZ_IN) * 2;  // 104 MiB

  dim3 cblk(256);
  dim3 ggq(24, 64);
  dim3 ggs(8, 64);
  dim3 agrid(BATCH * NH, SEQ / 128);

  if (ws_size >= NEED_FUSED) {
    u16* in_c  = (u16*)d_ws;
    u16* w3    = in_c + 3 * SZ_IN;
    u16* wo_c  = w3   + 3 * SZ_W;
    u16* q_ws  = wo_c + SZ_W;
    u16* k_ws  = q_ws + SZ_IN;
    u16* vt_ws = k_ws + SZ_IN;
    u16* ctx   = in_c;

    cast_all<<<14336, cblk, 0, stream>>>(q, k, v, Wq, Wk, Wv, Wo, in_c, w3, wo_c);
    gemm_k<0><<<ggq, cblk, 0, stream>>>(in_c, in_c + SZ_IN, in_c + 2 * SZ_IN, w3,
                                        bq, bk, bv, q_ws, k_ws, vt_ws, nullptr, 0);
    attn3<<<agrid, cblk, 0, stream>>>(q_ws, k_ws, vt_ws, ctx);
    gemm_k<1><<<ggs, cblk, 0, stream>>>(ctx, ctx, ctx, wo_c,
                                        bo, bo, bo, nullptr, nullptr, nullptr,
                                        (float*)d_out, 0);
  } else {
    u16* in_c  = (u16*)d_ws;
    u16* w3    = in_c + SZ_IN;
    u16* wo_c  = w3   + 3 * SZ_W;
    u16* q_ws  = wo_c + SZ_W;
    u16* k_ws  = q_ws + SZ_IN;
    u16* vt_ws = k_ws + SZ_IN;
    u16* ctx   = in_c;

    const int NA8 = MTOT * DM / 8;
    cast_w<<<2048, cblk, 0, stream>>>(Wq, Wk, Wv, Wo, w3, wo_c);
    cast_bf16<<<NA8 / 256, cblk, 0, stream>>>(q, in_c, NA8);
    gemm_k<0><<<ggs, cblk, 0, stream>>>(in_c, in_c, in_c, w3, bq, bk, bv,
                                        q_ws, k_ws, vt_ws, nullptr, 0);
    cast_bf16<<<NA8 / 256, cblk, 0, stream>>>(k, in_c, NA8);
    gemm_k<0><<<ggs, cblk, 0, stream>>>(in_c, in_c, in_c, w3, bq, bk, bv,
                                        q_ws, k_ws, vt_ws, nullptr, 1);
    cast_bf16<<<NA8 / 256, cblk, 0, stream>>>(v, in_c, NA8);
    gemm_k<0><<<ggs, cblk, 0, stream>>>(in_c, in_c, in_c, w3, bq, bk, bv,
                                        q_ws, k_ws, vt_ws, nullptr, 2);
    attn3<<<agrid, cblk, 0, stream>>>(q_ws, k_ws, vt_ws, ctx);
    gemm_k<1><<<ggs, cblk, 0, stream>>>(ctx, ctx, ctx, wo_c,
                                        bo, bo, bo, nullptr, nullptr, nullptr,
                                        (float*)d_out, 0);
  }
}